// Round 2
// 627.850 us; speedup vs baseline: 1.1538x; 1.1538x over previous
//
#include <hip/hip_runtime.h>

#define B_ 16
#define H_ 12
#define N_ 784
#define NN_ (N_ * N_)      // 614656
#define NF4_ (N_ / 4)      // 196 float4 per row
#define BPB_ 128           // blocks per batch for finalize pass

// ws layout: float2 stats[B_*N_]  -> (rowmax, rowexpsum) per (b,i) row. ~100 KB.

// ---- pass 1: fused rowsum + head-weighted aggregate + per-row online-softmax stats ----
// One wave per (b,i) row. Head loop unrolled only 2-deep to cap VGPR pressure
// (full unroll invites the compiler to hoist up to 12x16 VGPRs of row data).
__global__ __launch_bounds__(256) void agg_stats_kernel(
    const float* __restrict__ m, float* __restrict__ agg,
    float2* __restrict__ stats) {
    const int lane = threadIdx.x & 63;
    const int wave = threadIdx.x >> 6;
    const int row  = blockIdx.x * 4 + wave;   // row index in [0, B*N)
    const int b = row / N_;
    const int i = row - b * N_;

    float4 a0 = make_float4(0.f, 0.f, 0.f, 0.f);
    float4 a1 = a0, a2 = a0, a3 = a0;

#pragma unroll 2
    for (int h = 0; h < H_; ++h) {
        const float4* p =
            (const float4*)m + ((size_t)(b * H_ + h) * N_ + i) * NF4_;
        float4 r0 = p[lane];
        float4 r1 = p[lane + 64];
        float4 r2 = p[lane + 128];
        float4 r3 = (lane < NF4_ - 192) ? p[lane + 192]
                                        : make_float4(0.f, 0.f, 0.f, 0.f);
        float s = ((r0.x + r0.y) + (r0.z + r0.w))
                + ((r1.x + r1.y) + (r1.z + r1.w))
                + ((r2.x + r2.y) + (r2.z + r2.w))
                + ((r3.x + r3.y) + (r3.z + r3.w));
#pragma unroll
        for (int off = 32; off > 0; off >>= 1) s += __shfl_xor(s, off, 64);
        a0.x += r0.x * s; a0.y += r0.y * s; a0.z += r0.z * s; a0.w += r0.w * s;
        a1.x += r1.x * s; a1.y += r1.y * s; a1.z += r1.z * s; a1.w += r1.w * s;
        a2.x += r2.x * s; a2.y += r2.y * s; a2.z += r2.z * s; a2.w += r2.w * s;
        a3.x += r3.x * s; a3.y += r3.y * s; a3.z += r3.z * s; a3.w += r3.w * s;
    }

    float4* outp = (float4*)agg + ((size_t)b * N_ + i) * NF4_;
    outp[lane]       = a0;
    outp[lane + 64]  = a1;
    outp[lane + 128] = a2;
    if (lane < NF4_ - 192) outp[lane + 192] = a3;

    // per-lane max over valid elements (all values >= 0, so 0-init is safe)
    float mx = fmaxf(fmaxf(fmaxf(a0.x, a0.y), fmaxf(a0.z, a0.w)),
                     fmaxf(fmaxf(a1.x, a1.y), fmaxf(a1.z, a1.w)));
    mx = fmaxf(mx, fmaxf(fmaxf(a2.x, a2.y), fmaxf(a2.z, a2.w)));
    if (lane < NF4_ - 192)
        mx = fmaxf(mx, fmaxf(fmaxf(a3.x, a3.y), fmaxf(a3.z, a3.w)));

    // per-lane sum of exp(v - mx) over valid elements
    float es = __expf(a0.x - mx) + __expf(a0.y - mx)
             + __expf(a0.z - mx) + __expf(a0.w - mx)
             + __expf(a1.x - mx) + __expf(a1.y - mx)
             + __expf(a1.z - mx) + __expf(a1.w - mx)
             + __expf(a2.x - mx) + __expf(a2.y - mx)
             + __expf(a2.z - mx) + __expf(a2.w - mx);
    if (lane < NF4_ - 192)
        es += __expf(a3.x - mx) + __expf(a3.y - mx)
            + __expf(a3.z - mx) + __expf(a3.w - mx);

    // joint (max, expsum) butterfly across the wave
#pragma unroll
    for (int off = 32; off > 0; off >>= 1) {
        float om = __shfl_xor(mx, off, 64);
        float os = __shfl_xor(es, off, 64);
        float nm = fmaxf(mx, om);
        es = es * __expf(mx - nm) + os * __expf(om - nm);
        mx = nm;
    }
    if (lane == 0) stats[row] = make_float2(mx, es);
}

// ---- pass 2: per-batch stat reduce (redundant per block, deterministic) + exp-scale ----
__global__ __launch_bounds__(256) void finalize_kernel(
    float* __restrict__ agg, const float2* __restrict__ stats) {
    const int b   = blockIdx.x / BPB_;
    const int blk = blockIdx.x % BPB_;

    // reduce this batch's 784 (m, s) pairs; all values >= 0 so 0-init is safe
    float mR = 0.f, sR = 0.f;
    for (int r = threadIdx.x; r < N_; r += 256) {
        float2 t = stats[b * N_ + r];
        float nm = fmaxf(mR, t.x);
        sR = sR * __expf(mR - nm) + t.y * __expf(t.x - nm);
        mR = nm;
    }
#pragma unroll
    for (int off = 32; off > 0; off >>= 1) {
        float om = __shfl_xor(mR, off, 64);
        float os = __shfl_xor(sR, off, 64);
        float nm = fmaxf(mR, om);
        sR = sR * __expf(mR - nm) + os * __expf(om - nm);
        mR = nm;
    }
    __shared__ float2 red[4];
    if ((threadIdx.x & 63) == 0) red[threadIdx.x >> 6] = make_float2(mR, sR);
    __syncthreads();
    float2 p0 = red[0], p1 = red[1], p2 = red[2], p3 = red[3];
    const float gm = fmaxf(fmaxf(p0.x, p1.x), fmaxf(p2.x, p3.x));
    const float S  = p0.y * __expf(p0.x - gm) + p1.y * __expf(p1.x - gm)
                   + p2.y * __expf(p2.x - gm) + p3.y * __expf(p3.x - gm);
    const float inv = 1.0f / S;

    float4* p = (float4*)agg + (size_t)b * (NN_ / 4);
    for (int idx = blk * 256 + threadIdx.x; idx < NN_ / 4; idx += BPB_ * 256) {
        float4 v = p[idx];
        v.x = __expf(v.x - gm) * inv;
        v.y = __expf(v.y - gm) * inv;
        v.z = __expf(v.z - gm) * inv;
        v.w = __expf(v.w - gm) * inv;
        p[idx] = v;
    }
}

extern "C" void kernel_launch(void* const* d_in, const int* in_sizes, int n_in,
                              void* d_out, int out_size, void* d_ws,
                              size_t ws_size, hipStream_t stream) {
    const float* m = (const float*)d_in[0];
    float* out = (float*)d_out;            // doubles as agg scratch
    float2* stats = (float2*)d_ws;         // B_*N_ float2 = ~100 KB

    hipLaunchKernelGGL(agg_stats_kernel, dim3(B_ * N_ / 4), dim3(256), 0,
                       stream, m, out, stats);
    hipLaunchKernelGGL(finalize_kernel, dim3(B_ * BPB_), dim3(256), 0,
                       stream, out, stats);
}